// Round 2
// 551.981 us; speedup vs baseline: 1.0051x; 1.0051x over previous
//
#include <hip/hip_runtime.h>
#include <hip/hip_bf16.h>
#include <stdint.h>

#define MDIM 8192
#define NDIM 4096
#define KDIM 4096

#define BM 256
#define BN 256
#define BK 64

typedef short bf16x8 __attribute__((ext_vector_type(8)));
typedef float floatx4 __attribute__((ext_vector_type(4)));

__device__ __forceinline__ unsigned short f2bf(float f) {
    union { __hip_bfloat16 h; unsigned short u; } v;
    v.h = __float2bfloat16(f);
    return v.u;
}

__device__ __forceinline__ float bf2f(unsigned short u) {
    union { unsigned int i; float f; } v;
    v.i = ((unsigned int)u) << 16;
    return v.f;
}

// ---------- fp32 -> bf16 bulk convert (8 elements / thread / iter) ----------
__global__ __launch_bounds__(256) void cvt_bf16(
    const float* __restrict__ in, unsigned short* __restrict__ out, int n8) {
    int idx = blockIdx.x * blockDim.x + threadIdx.x;
    int stride = gridDim.x * blockDim.x;
    for (int i = idx; i < n8; i += stride) {
        const float4* p = (const float4*)in + (size_t)i * 2;
        float4 a = p[0], b = p[1];
        bf16x8 o;
        o[0] = (short)f2bf(a.x); o[1] = (short)f2bf(a.y);
        o[2] = (short)f2bf(a.z); o[3] = (short)f2bf(a.w);
        o[4] = (short)f2bf(b.x); o[5] = (short)f2bf(b.y);
        o[6] = (short)f2bf(b.z); o[7] = (short)f2bf(b.w);
        *((bf16x8*)out + i) = o;
    }
}

// ---------- xa[m,r] = (1/16) * sum_k x[m,k]*A[r,k] ----------
__global__ __launch_bounds__(256) void lora_xa(
    const unsigned short* __restrict__ xc,  // [M,K] bf16
    const float* __restrict__ A,            // [16,K] fp32
    const float* __restrict__ Bf,           // [N,16] fp32
    unsigned short* __restrict__ xa,        // [M,16] bf16 out (prescaled)
    unsigned short* __restrict__ Bc) {      // [N,16] bf16 out
    const int gt = blockIdx.x * blockDim.x + threadIdx.x;
    if (gt < 8192) {  // B convert: 65536 elems = 8192 chunks of 8
        const float4* p = (const float4*)Bf + (size_t)gt * 2;
        float4 a = p[0], b = p[1];
        bf16x8 o;
        o[0] = (short)f2bf(a.x); o[1] = (short)f2bf(a.y);
        o[2] = (short)f2bf(a.z); o[3] = (short)f2bf(a.w);
        o[4] = (short)f2bf(b.x); o[5] = (short)f2bf(b.y);
        o[6] = (short)f2bf(b.z); o[7] = (short)f2bf(b.w);
        *((bf16x8*)Bc + gt) = o;
    }

    const int lane = threadIdx.x & 63;
    const int wave = gt >> 6;           // 2048 waves, 4 rows each
    const int m0 = wave * 4;
    if (m0 >= MDIM) return;

    float acc[4][16];
#pragma unroll
    for (int q = 0; q < 4; ++q)
#pragma unroll
        for (int r = 0; r < 16; ++r) acc[q][r] = 0.f;

    for (int k = lane * 4; k < KDIM; k += 256) {
        float xf[4][4];
#pragma unroll
        for (int q = 0; q < 4; ++q) {
            short4 xv = *(const short4*)(xc + (size_t)(m0 + q) * KDIM + k);
            xf[q][0] = bf2f((unsigned short)xv.x);
            xf[q][1] = bf2f((unsigned short)xv.y);
            xf[q][2] = bf2f((unsigned short)xv.z);
            xf[q][3] = bf2f((unsigned short)xv.w);
        }
#pragma unroll
        for (int r = 0; r < 16; ++r) {
            float4 av = *(const float4*)(A + (size_t)r * KDIM + k);
#pragma unroll
            for (int q = 0; q < 4; ++q)
                acc[q][r] += xf[q][0] * av.x + xf[q][1] * av.y +
                             xf[q][2] * av.z + xf[q][3] * av.w;
        }
    }
#pragma unroll
    for (int q = 0; q < 4; ++q)
#pragma unroll
        for (int r = 0; r < 16; ++r) {
#pragma unroll
            for (int off = 32; off > 0; off >>= 1)
                acc[q][r] += __shfl_xor(acc[q][r], off, 64);
        }
    if (lane == 0) {
        const float scale = 1.0f / 16.0f;
#pragma unroll
        for (int q = 0; q < 4; ++q)
#pragma unroll
            for (int r = 0; r < 16; ++r)
                xa[(size_t)(m0 + q) * 16 + r] = f2bf(acc[q][r] * scale);
    }
}

// ---------- 256x256 bf16 GEMM, 4-phase pipelined schedule, counted vmcnt ----
// LDS slot layout per tile: 16B chunk (row, cc) lives at slot row*8 + (cc ^ (row&7)).
// DMA dest stays linear (wave-uniform base + lane*16); the global SOURCE chunk is
// permuted (scc) so reads with the XOR'd slot come back conflict-free.
//
// Schedule per K-tile n (4 phases). Stage rotation (1 half-tile = 2 loads/phase):
//   P1: read bF0,aA   | stage A0(n+1) -> other buf | MFMA i0-3 x s0
//   P2: read bF1,aB   | stage A1(n+1) -> other buf | MFMA i0-3 x s1
//   P3: read aC       | stage B0(n+2) -> this buf  | MFMA i4-7 x s0
//   P4: read aD       | stage B1(n+2) -> this buf  | vmcnt(4) | MFMA i4-7 x s1
// Region safety: B reads of tile n finish at P2 (B0/B1 overwritten P3/P4, after
// barriers); A reads finish at P4 (A0/A1 overwritten at P1/P2 of n+1). vmcnt(4)
// at P4 leaves only B0,B1(n+2) in flight => tile n+1 fully landed before its P1.
__device__ __forceinline__ void stage_half(
    const unsigned short* __restrict__ gp, unsigned short* lb,
    int row0, int kt, int h, int wave, int srow, int scc) {
#pragma unroll
    for (int l = 0; l < 2; ++l) {
        const int cbase = h * 1024 + l * 512 + wave * 64;   // chunk base (wave-uniform)
        const int row = (cbase >> 3) + srow;                // h*128 + l*64 + wave*8 + srow
        __builtin_amdgcn_global_load_lds(
            (const __attribute__((address_space(1))) unsigned int*)(gp + (size_t)(row0 + row) * KDIM + kt * BK + scc * 8),
            (__attribute__((address_space(3))) unsigned int*)&lb[cbase * 8], 16, 0, 0);
    }
}

__global__ __launch_bounds__(512, 2) void lora_gemm(
    const unsigned short* __restrict__ x,   // [M,K] bf16
    const unsigned short* __restrict__ W,   // [N,K] bf16
    const float* __restrict__ bias,         // [N] fp32
    const unsigned short* __restrict__ Bl,  // [N,16] bf16
    const unsigned short* __restrict__ xa,  // [M,16] bf16 (prescaled)
    float* __restrict__ out) {              // [M,N] fp32
    __shared__ __align__(16) unsigned short lA[2][BM * BK];   // 2 x 32 KiB
    __shared__ __align__(16) unsigned short lB[2][BN * BK];   // 2 x 32 KiB

    // XCD-aware swizzle: 512 wgs, 64 per XCD get a contiguous chunk (bijective).
    int wg = blockIdx.y * 16 + blockIdx.x;
    wg = (wg & 7) * 64 + (wg >> 3);
    const int bn = (wg & 15) * BN;
    const int bm = (wg >> 4) * BM;

    const int t = threadIdx.x;
    const int lane = t & 63;
    const int wave = t >> 6;                // 8 waves: 2 (M) x 4 (N)
    const int wm = (wave >> 2) * 128;       // wave M offset in tile
    const int wn = (wave & 3) * 64;         // wave N offset in tile
    const int fr = lane & 15;
    const int fq = lane >> 4;
    const int f7 = fr & 7;
    const int srow = lane >> 3;
    const int scc = (lane & 7) ^ srow;      // per-lane source chunk permutation

    const int sl0 = (fq ^ f7) << 3;         // k-step 0 slot offset (elems)
    const int sl1 = ((4 + fq) ^ f7) << 3;   // k-step 1 slot offset
    const int aoff = (wm + fr) * BK;
    const int boff = (wn + fr) * BK;

    floatx4 acc[8][4];
#pragma unroll
    for (int i = 0; i < 8; ++i)
#pragma unroll
        for (int j = 0; j < 4; ++j)
            acc[i][j] = (floatx4){0.f, 0.f, 0.f, 0.f};

    // LoRA delta seed: one rank-16 MFMA step, fragments direct from global,
    // zero-padded to K=32 in registers (fq>=2 lanes hold zeros).
    {
        bf16x8 z = {0, 0, 0, 0, 0, 0, 0, 0};
        bf16x8 af[8], bfv[4];
#pragma unroll
        for (int i = 0; i < 8; ++i) {
            int row = bm + wm + i * 16 + fr;
            af[i] = (fq < 2) ? *(const bf16x8*)(xa + (size_t)row * 16 + fq * 8) : z;
        }
#pragma unroll
        for (int j = 0; j < 4; ++j) {
            int row = bn + wn + j * 16 + fr;
            bfv[j] = (fq < 2) ? *(const bf16x8*)(Bl + (size_t)row * 16 + fq * 8) : z;
        }
#pragma unroll
        for (int i = 0; i < 8; ++i)
#pragma unroll
            for (int j = 0; j < 4; ++j)
                acc[i][j] = __builtin_amdgcn_mfma_f32_16x16x32_bf16(af[i], bfv[j], acc[i][j], 0, 0, 0);
    }

    // Prologue: tile 0 fully + B halves of tile 1  (6 half-tiles = 12 loads).
    stage_half(x, lA[0], bm, 0, 0, wave, srow, scc);
    stage_half(x, lA[0], bm, 0, 1, wave, srow, scc);
    stage_half(W, lB[0], bn, 0, 0, wave, srow, scc);
    stage_half(W, lB[0], bn, 0, 1, wave, srow, scc);
    stage_half(W, lB[1], bn, 1, 0, wave, srow, scc);
    stage_half(W, lB[1], bn, 1, 1, wave, srow, scc);
    asm volatile("s_waitcnt vmcnt(4)" ::: "memory");   // tile 0 landed; B(1) in flight
    __builtin_amdgcn_s_barrier();

#pragma unroll 2
    for (int n = 0; n < KDIM / BK; ++n) {
        const int cur = n & 1;
        const unsigned short* la = lA[cur];
        const unsigned short* lb = lB[cur];
        bf16x8 bF0[4], bF1[4], aA[4], aB[4], aC[4], aD[4];

        // ---------------- P1: bF0 + aA, stage A0(n+1), MFMA i0-3 s0 ----------
#pragma unroll
        for (int j = 0; j < 4; ++j)
            bF0[j] = *(const bf16x8*)&lb[boff + j * 16 * BK + sl0];
#pragma unroll
        for (int i = 0; i < 4; ++i)
            aA[i] = *(const bf16x8*)&la[aoff + i * 16 * BK + sl0];
        if (n < 63) stage_half(x, lA[cur ^ 1], bm, n + 1, 0, wave, srow, scc);
        __builtin_amdgcn_s_barrier();
        asm volatile("s_waitcnt lgkmcnt(0)" ::: "memory");
        __builtin_amdgcn_sched_barrier(0);
        __builtin_amdgcn_s_setprio(1);
#pragma unroll
        for (int i = 0; i < 4; ++i)
#pragma unroll
            for (int j = 0; j < 4; ++j)
                acc[i][j] = __builtin_amdgcn_mfma_f32_16x16x32_bf16(aA[i], bF0[j], acc[i][j], 0, 0, 0);
        __builtin_amdgcn_s_setprio(0);
        __builtin_amdgcn_s_barrier();

        // ---------------- P2: bF1 + aB, stage A1(n+1), MFMA i0-3 s1 ----------
#pragma unroll
        for (int j = 0; j < 4; ++j)
            bF1[j] = *(const bf16x8*)&lb[boff + j * 16 * BK + sl1];
#pragma unroll
        for (int i = 0; i < 4; ++i)
            aB[i] = *(const bf16x8*)&la[aoff + i * 16 * BK + sl1];
        if (n < 63) stage_half(x, lA[cur ^ 1], bm, n + 1, 1, wave, srow, scc);
        __builtin_amdgcn_s_barrier();
        asm volatile("s_waitcnt lgkmcnt(0)" ::: "memory");
        __builtin_amdgcn_sched_barrier(0);
        __builtin_amdgcn_s_setprio(1);
#pragma unroll
        for (int i = 0; i < 4; ++i)
#pragma unroll
            for (int j = 0; j < 4; ++j)
                acc[i][j] = __builtin_amdgcn_mfma_f32_16x16x32_bf16(aB[i], bF1[j], acc[i][j], 0, 0, 0);
        __builtin_amdgcn_s_setprio(0);
        __builtin_amdgcn_s_barrier();

        // ---------------- P3: aC, stage B0(n+2), MFMA i4-7 s0 ----------------
#pragma unroll
        for (int i = 0; i < 4; ++i)
            aC[i] = *(const bf16x8*)&la[aoff + 64 * BK + i * 16 * BK + sl0];
        if (n < 62) stage_half(W, lB[cur], bn, n + 2, 0, wave, srow, scc);
        __builtin_amdgcn_s_barrier();
        asm volatile("s_waitcnt lgkmcnt(0)" ::: "memory");
        __builtin_amdgcn_sched_barrier(0);
        __builtin_amdgcn_s_setprio(1);
#pragma unroll
        for (int i = 0; i < 4; ++i)
#pragma unroll
            for (int j = 0; j < 4; ++j)
                acc[4 + i][j] = __builtin_amdgcn_mfma_f32_16x16x32_bf16(aC[i], bF0[j], acc[4 + i][j], 0, 0, 0);
        __builtin_amdgcn_s_setprio(0);
        __builtin_amdgcn_s_barrier();

        // ---------------- P4: aD, stage B1(n+2), vmcnt, MFMA i4-7 s1 ---------
#pragma unroll
        for (int i = 0; i < 4; ++i)
            aD[i] = *(const bf16x8*)&la[aoff + 64 * BK + i * 16 * BK + sl1];
        if (n < 62) stage_half(W, lB[cur], bn, n + 2, 1, wave, srow, scc);
        if (n < 62) { asm volatile("s_waitcnt vmcnt(4)" ::: "memory"); }
        else        { asm volatile("s_waitcnt vmcnt(0)" ::: "memory"); }
        __builtin_amdgcn_s_barrier();
        asm volatile("s_waitcnt lgkmcnt(0)" ::: "memory");
        __builtin_amdgcn_sched_barrier(0);
        __builtin_amdgcn_s_setprio(1);
#pragma unroll
        for (int i = 0; i < 4; ++i)
#pragma unroll
            for (int j = 0; j < 4; ++j)
                acc[4 + i][j] = __builtin_amdgcn_mfma_f32_16x16x32_bf16(aD[i], bF1[j], acc[4 + i][j], 0, 0, 0);
        __builtin_amdgcn_s_setprio(0);
        __builtin_amdgcn_s_barrier();
    }

    // Epilogue: D layout col=lane&15, row=(lane>>4)*4+reg. Add fp32 bias, store fp32.
#pragma unroll
    for (int j = 0; j < 4; ++j) {
        int col = bn + wn + j * 16 + fr;
        float bv = bias[col];
#pragma unroll
        for (int i = 0; i < 8; ++i) {
            int row0 = bm + wm + i * 16 + fq * 4;
#pragma unroll
            for (int r = 0; r < 4; ++r) {
                out[(size_t)(row0 + r) * NDIM + col] = acc[i][j][r] + bv;
            }
        }
    }
}

extern "C" void kernel_launch(void* const* d_in, const int* in_sizes, int n_in,
                              void* d_out, int out_size, void* d_ws, size_t ws_size,
                              hipStream_t stream) {
    const float* x    = (const float*)d_in[0];  // [4,2048,4096] fp32
    const float* W    = (const float*)d_in[1];  // [4096,4096] fp32
    const float* bias = (const float*)d_in[2];  // [4096] fp32
    const float* A    = (const float*)d_in[3];  // [16,4096] fp32
    const float* Bf   = (const float*)d_in[4];  // [4096,16] fp32
    float* out = (float*)d_out;                 // [8192,4096] fp32

    unsigned short* xc = (unsigned short*)d_ws;              // 64 MB
    unsigned short* Wc = xc + (size_t)MDIM * KDIM;           // 32 MB
    unsigned short* xa = Wc + (size_t)NDIM * KDIM;           // 256 KB
    unsigned short* Bc = xa + (size_t)MDIM * 16;             // 128 KB

    cvt_bf16<<<8192, 256, 0, stream>>>(x, xc, (MDIM * KDIM) / 8);
    cvt_bf16<<<4096, 256, 0, stream>>>(W, Wc, (NDIM * KDIM) / 8);
    lora_xa<<<512, 256, 0, stream>>>(xc, A, Bf, xa, Bc);
    lora_gemm<<<dim3(NDIM / BN, MDIM / BM), 512, 0, stream>>>(xc, Wc, bias, Bc, xa, out);
}